// Round 5
// baseline (231.938 us; speedup 1.0000x reference)
//
#include <hip/hip_runtime.h>

#define BATCH 128
#define NPTS  4096
#define EPT   8                    // cells per thread
#define WREG  (64 * EPT)           // 512-cell compute region per wave
#define HALOC 104                  // halo cells per side (>= 99 steps of contamination)
#define OWN   (WREG - 2 * HALOC)   // 304 owned cells per interior wave
#define SEGS  14                   // ceil(4096 / 304); edge segs clamp to domain
#define TPB   64                   // one independent wave per block

typedef float v4f __attribute__((ext_vector_type(4)));  // clang vector: valid for
                                                        // __builtin_nontemporal_store

// Halved-coefficient flux: g(u) = 0.5*f(u), ah(u) = 0.5*|f'(u)|
// f  = 1.5u + 0.75b u^2 + (-0.5-2b) u^3 + 1.5b u^4 - 0.25b u^6,  b = beta/12
// f' = 1.5 + 1.5b u - (1.5+6b) u^2 + 6b u^3 - 1.5b u^5
__device__ __forceinline__ void flux_eval(float u, float& g, float& ah) {
    constexpr float b  = 0.1f / 12.0f;
    constexpr float c6 = 0.5f * (-0.25f * b);
    constexpr float c4 = 0.5f * ( 1.5f  * b);
    constexpr float c3 = 0.5f * (-0.5f - 2.0f * b);
    constexpr float c2 = 0.5f * ( 0.75f * b);
    constexpr float c1 = 0.5f * ( 1.5f);
    constexpr float d5 = 0.5f * (-1.5f * b);
    constexpr float d3 = 0.5f * ( 6.0f * b);
    constexpr float d2 = 0.5f * (-(1.5f + 6.0f * b));
    constexpr float d1 = 0.5f * ( 1.5f * b);
    constexpr float d0 = 0.5f * ( 1.5f);

    float t = c6 * u;            // c5 == 0
    t = fmaf(t, u, c4);
    t = fmaf(t, u, c3);
    t = fmaf(t, u, c2);
    t = fmaf(t, u, c1);
    g = u * t;

    float e = d5 * u;            // d4 == 0
    e = fmaf(e, u, d3);
    e = fmaf(e, u, d2);
    e = fmaf(e, u, d1);
    e = fmaf(e, u, d0);
    ah = fabsf(e);
}

// One local-Lax-Friedrichs step: dst = step(src). dst/src are DISTINCT register
// sets (rotation) so in-flight stores of older sets are never WAR-blocked by
// the newest update — the compiler's auto-waitcnt then targets only the
// oldest outstanding stores (deep pipeline) instead of vmcnt(0) every step.
__device__ __forceinline__ void pde_step(float (&dst)[EPT], const float (&src)[EPT],
                                         const bool bcL, const bool bcR) {
    const float vl = __shfl_up(src[EPT - 1], 1, 64);
    const float vr = __shfl_down(src[0], 1, 64);

    float vv[EPT + 2];
    vv[0] = vl;
#pragma unroll
    for (int i = 0; i < EPT; ++i) vv[i + 1] = src[i];
    vv[EPT + 1] = vr;

    float g[EPT + 2], a[EPT + 2];
#pragma unroll
    for (int i = 0; i < EPT + 2; ++i) flux_eval(vv[i], g[i], a[i]);

    float fh[EPT + 1];
#pragma unroll
    for (int m = 0; m < EPT + 1; ++m)
        fh[m] = g[m] + g[m + 1] - fmaxf(a[m], a[m + 1]) * (vv[m + 1] - vv[m]);

#pragma unroll
    for (int i = 0; i < EPT; ++i)                  // r = DT/DX = 0.5 exactly
        dst[i] = fmaf(-0.5f, fh[i + 1] - fh[i], src[i]);

    if (bcL) dst[0] = dst[1];                      // u_new[0]   = u_new[1]
    if (bcR) dst[EPT - 1] = dst[EPT - 2];          // u_new[N-1] = u_new[N-2]
}

__device__ __forceinline__ void st8(float* p, const float (&u)[EPT]) {
    v4f lo = {u[0], u[1], u[2], u[3]};
    v4f hi = {u[4], u[5], u[6], u[7]};
    __builtin_nontemporal_store(lo, (v4f*)p);
    __builtin_nontemporal_store(hi, (v4f*)(p + 4));
}

__global__ __launch_bounds__(TPB) void pde_wave_pipe(
        const float* __restrict__ init,
        const int*   __restrict__ stepnum_p,
        float*       __restrict__ out) {
    const int wid  = blockIdx.x;
    const int lane = threadIdx.x;
    const int row  = wid / SEGS;
    const int seg  = wid - row * SEGS;

    const int ownlo = seg * OWN;
    const int base  = min(max(ownlo - HALOC, 0), NPTS - WREG);
    const int c0    = base + lane * EPT;               // 32B-aligned
    const bool ownstore = (c0 >= ownlo) && (c0 < ownlo + OWN) && (c0 < NPTS);
    const bool bcL = (seg == 0) && (lane == 0);
    const bool bcR = (seg == SEGS - 1) && (lane == 63);
    const int stepnum = *stepnum_p;

    const float* ip = init + (size_t)row * NPTS + c0;
    const v4f A  = *(const v4f*)ip;
    const v4f Bv = *(const v4f*)(ip + 4);
    float v[EPT] = {A.x, A.y, A.z, A.w, Bv.x, Bv.y, Bv.z, Bv.w};
    float w[EPT], x[EPT], y[EPT];                      // rotation sets (written first)

    const size_t Z = (size_t)BATCH * NPTS;
    float* op = out + (size_t)row * NPTS + c0;

    if (ownstore) {                                    // out[step=0] = init verbatim
        __builtin_nontemporal_store(A,  (v4f*)op);
        __builtin_nontemporal_store(Bv, (v4f*)(op + 4));
    }
    op += Z;                                           // points at step s=1 slot

    int s = 1;
    // 4-deep time unroll: each state set's registers are redefined 4 steps
    // after their store, so store-ack latency is hidden by ~3 steps of compute.
    for (; s + 3 < stepnum; s += 4) {
        pde_step(w, v, bcL, bcR); if (ownstore) st8(op,         w);
        pde_step(x, w, bcL, bcR); if (ownstore) st8(op + Z,     x);
        pde_step(y, x, bcL, bcR); if (ownstore) st8(op + 2 * Z, y);
        pde_step(v, y, bcL, bcR); if (ownstore) st8(op + 3 * Z, v);
        op += 4 * Z;
    }
    // tail (stepnum=100 -> 99 steps -> 3 remaining), still rotation, no copies
    if (s < stepnum) {
        pde_step(w, v, bcL, bcR); if (ownstore) st8(op, w); op += Z; ++s;
        if (s < stepnum) {
            pde_step(x, w, bcL, bcR); if (ownstore) st8(op, x); op += Z; ++s;
            if (s < stepnum) {
                pde_step(y, x, bcL, bcR); if (ownstore) st8(op, y);
            }
        }
    }
}

extern "C" void kernel_launch(void* const* d_in, const int* in_sizes, int n_in,
                              void* d_out, int out_size, void* d_ws, size_t ws_size,
                              hipStream_t stream) {
    const float* init  = (const float*)d_in[0];
    const int*   steps = (const int*)d_in[1];
    float*       out   = (float*)d_out;
    pde_wave_pipe<<<BATCH * SEGS, TPB, 0, stream>>>(init, steps, out);
}